// Round 3
// baseline (704.710 us; speedup 1.0000x reference)
//
#include <hip/hip_runtime.h>

// EdgeEmbAttentionAggregator: fused GAT-style aggregation. FLOAT32 I/O.
// Algebraic restructuring: neighs@a_n = neigh_feat@(W2@a_n); h_prime = agg@W2
// where agg = sum_s att[s]*neigh_feat[n,s,:]. Avoids materializing (N*S,64).

#define NGS 136   // LDS row stride for 128-wide neigh tile (+8 pad)
#define EES 40    // LDS row stride for 32-wide edge tile

// ws layout (fp32): [0:128) w2a = W2 @ a_n ; [128:288) copy of a[0:160)
__global__ __launch_bounds__(256)
void prep_kernel(const float* __restrict__ W2,
                 const float* __restrict__ a,
                 float* __restrict__ ws) {
    const int t = threadIdx.x;
    __shared__ float s_a[160];
    if (t < 160) { float v = a[t]; s_a[t] = v; ws[128 + t] = v; }
    __syncthreads();
    if (t < 128) {
        float p = 0.f;
        #pragma unroll
        for (int d = 0; d < 64; d++) p = fmaf(W2[t * 64 + d], s_a[64 + d], p);
        ws[t] = p;
    }
}

__global__ __launch_bounds__(256)
void gat_kernel(const float* __restrict__ input,
                const float* __restrict__ neigh,
                const float* __restrict__ edge,
                const float* __restrict__ W,
                const float* __restrict__ W2,
                const float* __restrict__ ws,
                float* __restrict__ out,
                int N) {
    const int t = threadIdx.x;
    const int d = t & 63;        // output column this thread owns (x / h')
    const int q = t >> 6;        // which quarter of K (wave id)

    __shared__ float s_ws[288];
    __shared__ float s_in[128];
    __shared__ float s_ng[16 * NGS];
    __shared__ float s_ee[16 * EES];
    __shared__ float s_red[256];
    __shared__ float s_agg[128];
    __shared__ float s_sc[16];
    __shared__ float s_att[16];
    __shared__ __align__(16) float s_out[160];

    // ---- block-invariant setup: W/W2 columns into registers, ws into LDS
    float rW[32], rW2[32];
    {
        const int kb = q * 32;
        #pragma unroll
        for (int k = 0; k < 32; k++) {
            rW[k]  = W [(kb + k) * 64 + d];
            rW2[k] = W2[(kb + k) * 64 + d];
        }
    }
    s_ws[t] = ws[t];
    if (t < 32) s_ws[256 + t] = ws[256 + t];
    __syncthreads();

    for (int n = blockIdx.x; n < N; n += gridDim.x) {
        // ---- Phase L: stage node data into LDS
        {
            const float4* ng4 = (const float4*)(neigh + (size_t)n * 2048);
            #pragma unroll
            for (int i = 0; i < 2; i++) {
                const int idx = t + i * 256;          // 512 vec4 = 16x128
                const float4 v = ng4[idx];
                float* dst = s_ng + (idx >> 5) * NGS + ((idx & 31) << 2);
                dst[0] = v.x; dst[1] = v.y; dst[2] = v.z; dst[3] = v.w;
            }
            if (t < 128) {                            // 128 vec4 = 16x32
                const float4 v = ((const float4*)(edge + (size_t)n * 512))[t];
                float* dst = s_ee + (t >> 3) * EES + ((t & 7) << 2);
                dst[0] = v.x; dst[1] = v.y; dst[2] = v.z; dst[3] = v.w;
            } else if (t < 160) {                     // 32 vec4 = 128
                const int j = t - 128;
                const float4 v = ((const float4*)(input + (size_t)n * 128))[j];
                float* dst = s_in + (j << 2);
                dst[0] = v.x; dst[1] = v.y; dst[2] = v.z; dst[3] = v.w;
            }
        }
        __syncthreads();

        // ---- Phase A: x[d] partials (4 threads per d); Phase B: score partials
        {
            const int kb = q * 32;
            float p = 0.f;
            #pragma unroll
            for (int k = 0; k < 32; k++) p = fmaf(s_in[kb + k], rW[k], p);
            s_red[t] = p;
        }
        {
            const int s = t >> 4, g = t & 15;
            float p = 0.f;
            #pragma unroll
            for (int j = 0; j < 8; j++) {
                const int k = g + (j << 4);
                p = fmaf(s_ng[s * NGS + k], s_ws[k], p);        // · w2a
            }
            #pragma unroll
            for (int j = 0; j < 2; j++) {
                const int e = g + (j << 4);
                p = fmaf(s_ee[s * EES + e], s_ws[256 + e], p);  // · a_e
            }
            #pragma unroll
            for (int off = 8; off; off >>= 1) p += __shfl_down(p, off, 16);
            if (g == 0) s_sc[s] = p;
        }
        __syncthreads();

        // ---- Phase C (wave 0): finalize x, sx = x·a_x, leakyrelu+softmax
        if (t < 64) {
            const float x = s_red[t] + s_red[t + 64] + s_red[t + 128] + s_red[t + 192];
            s_out[t] = x;
            float p = x * s_ws[128 + t];              // a_x
            #pragma unroll
            for (int off = 32; off; off >>= 1) p += __shfl_down(p, off, 64);
            const float sx = __shfl(p, 0, 64);
            if (t < 16) {
                const float sc = sx + s_sc[t];
                const float e = sc > 0.f ? sc : 0.8f * sc;
                float m = e;
                #pragma unroll
                for (int off = 8; off; off >>= 1) m = fmaxf(m, __shfl_xor(m, off, 16));
                const float ex = __expf(e - m);
                float sum = ex;
                #pragma unroll
                for (int off = 8; off; off >>= 1) sum += __shfl_xor(sum, off, 16);
                s_att[t] = ex / sum;
            }
        }
        __syncthreads();

        // ---- Phase D: agg[k] = sum_s att[s]*neigh[s][k]; h_edge
        if (t < 128) {
            float p = 0.f;
            #pragma unroll
            for (int s = 0; s < 16; s++) p = fmaf(s_att[s], s_ng[s * NGS + t], p);
            s_agg[t] = p;
        } else if (t < 160) {
            const int e = t - 128;
            float p = 0.f;
            #pragma unroll
            for (int s = 0; s < 16; s++) p = fmaf(s_att[s], s_ee[s * EES + e], p);
            s_out[128 + e] = p;
        }
        __syncthreads();

        // ---- Phase E: h_prime[d] partials = agg @ W2
        {
            const int kb = q * 32;
            float p = 0.f;
            #pragma unroll
            for (int k = 0; k < 32; k++) p = fmaf(s_agg[kb + k], rW2[k], p);
            s_red[t] = p;
        }
        __syncthreads();

        // ---- Phase F: finalize h_prime
        if (t < 64)
            s_out[64 + t] = s_red[t] + s_red[t + 64] + s_red[t + 128] + s_red[t + 192];
        __syncthreads();   // s_out[64..127] must be visible to Phase G readers

        // ---- Phase G: vectorized row store (160 f32 = 40 x float4 = 640 B)
        if (t < 40)
            ((float4*)out)[(size_t)n * 40 + t] = ((const float4*)s_out)[t];
        // next iter's first write to any buffer read here is barrier-separated
    }
}

extern "C" void kernel_launch(void* const* d_in, const int* in_sizes, int n_in,
                              void* d_out, int out_size, void* d_ws, size_t ws_size,
                              hipStream_t stream) {
    const float* input = (const float*)d_in[0];
    const float* neigh = (const float*)d_in[1];
    const float* edge  = (const float*)d_in[2];
    const float* W     = (const float*)d_in[3];
    const float* W2    = (const float*)d_in[4];
    const float* a     = (const float*)d_in[5];
    float* ws = (float*)d_ws;
    float* out = (float*)d_out;

    const int N = in_sizes[0] / 128;   // 50000

    prep_kernel<<<1, 256, 0, stream>>>(W2, a, ws);
    gat_kernel<<<1280, 256, 0, stream>>>(input, neigh, edge, W, W2, ws, out, N);
}